// Round 1
// 184.945 us; speedup vs baseline: 1.0302x; 1.0302x over previous
//
#include <hip/hip_runtime.h>

typedef float floatx4 __attribute__((ext_vector_type(4)));
typedef __bf16 bf16x8 __attribute__((ext_vector_type(8)));
typedef __bf16 bf16x4 __attribute__((ext_vector_type(4)));
typedef short short4v __attribute__((ext_vector_type(4)));

#define MFMA16 __builtin_amdgcn_mfma_f32_16x16x32_bf16

static __device__ __forceinline__ short4v b2s(bf16x4 x) {
  union { bf16x4 b; short4v s; } u; u.b = x; return u.s;
}
// legacy K=16 bf16 MFMA: B-frag layout (col=l16, k=lq*4+j) matches the
// 16x16 C-frag of S^T directly -> P never touches LDS.
#define MFMAPV(a, b, c) \
  __builtin_amdgcn_mfma_f32_16x16x16bf16_1k(b2s(a), b2s(b), (c), 0, 0, 0)

typedef const __attribute__((address_space(1))) void* gas_t;
typedef __attribute__((address_space(3))) void* las_t;
#define GLD16(g, l) __builtin_amdgcn_global_load_lds((gas_t)(g), (las_t)(l), 16, 0, 0)

static __device__ __forceinline__ unsigned short f2bf(float f) {
  union { float f; unsigned int u; } v; v.f = f;
  unsigned int r = v.u + 0x7fffu + ((v.u >> 16) & 1u);
  return (unsigned short)(r >> 16);
}

// ---------------- fused prologue: cast x + transpose Wqkv + transpose Wproj -
static __device__ __forceinline__ void cast_transpose_tile(
    const float* __restrict__ in, unsigned short* __restrict__ out,
    int R, int C, int bx, int by) {
  const int r0 = by * 64, c0 = bx * 64;
  const int tid = threadIdx.x;
  __shared__ float tl[64][65];
  const int rr = tid >> 4, cc = (tid & 15) * 4;
#pragma unroll
  for (int i = 0; i < 4; ++i) {
    int row = rr + i * 16;
    float4 v = *(const float4*)(in + (size_t)(r0 + row) * C + c0 + cc);
    tl[row][cc] = v.x; tl[row][cc + 1] = v.y;
    tl[row][cc + 2] = v.z; tl[row][cc + 3] = v.w;
  }
  __syncthreads();
  const int cl = tid >> 2, rbase = (tid & 3) * 16;
  unsigned short o[16];
#pragma unroll
  for (int j = 0; j < 16; ++j) o[j] = f2bf(tl[rbase + j][cl]);
  unsigned short* dst = out + (size_t)(c0 + cl) * R + r0 + rbase;
  *(uint4*)dst = *(uint4*)o;
  *(uint4*)(dst + 8) = *(uint4*)(o + 8);
}

__global__ __launch_bounds__(256) void prologue_kernel(
    const float* __restrict__ x, unsigned short* __restrict__ Xb,
    const float* __restrict__ Wqkv, unsigned short* __restrict__ Wqkvt,
    const float* __restrict__ Wproj, unsigned short* __restrict__ Wprojt) {
  const int bid = blockIdx.x;
  if (bid < 4096) {
    int i = bid * 256 + threadIdx.x;
    float4 v = ((const float4*)x)[i];
    ushort4 o;
    o.x = f2bf(v.x); o.y = f2bf(v.y); o.z = f2bf(v.z); o.w = f2bf(v.w);
    ((ushort4*)Xb)[i] = o;
  } else if (bid < 4096 + 768) {
    int b2 = bid - 4096;
    cast_transpose_tile(Wqkv, Wqkvt, 1024, 3072, b2 % 48, b2 / 48);
  } else {
    int b3 = bid - 4096 - 768;
    cast_transpose_tile(Wproj, Wprojt, 1024, 1024, b3 % 16, b3 / 16);
  }
}

// ---------------- GEMM1: QKV = Xb @ WqkvT^T + bqkv, scatter -----------------
// Q[bh][t][d] (0.5*log2e folded), Kc[bh][t][d], Vt[bh][d][t].
// Epilogue bounces 64x64 wave-tiles through LDS (stride 72 = 144B, 16B-aligned
// rows) -> coalesced b128 stores. NOTE: t within batch = m0 & 2047 (batch is
// already encoded in bh) — raw m0 here was the round-8/9 corruption bug.
__global__ __launch_bounds__(256) void gemm_qkv(
    const unsigned short* __restrict__ A,
    const unsigned short* __restrict__ Bt,
    const float* __restrict__ bias,
    unsigned short* __restrict__ Q,
    unsigned short* __restrict__ Kc,
    unsigned short* __restrict__ Vt) {
  const int K = 1024;
  const int m0 = blockIdx.y * 128, n0 = blockIdx.x * 128;
  const int tid = threadIdx.x, w = tid >> 6, l = tid & 63;
  const int l16 = l & 15, lq = l >> 4;
  const int wm = w >> 1, wn = w & 1;
  const int which = n0 >> 10;

  __shared__ __align__(16) unsigned short SH[16384];
  unsigned short* As = SH;          // 128*64
  unsigned short* Bs = SH + 8192;   // 128*64

  floatx4 acc[4][4] = {};

  int sA[4], sB[4];
  unsigned ldso[4];
#pragma unroll
  for (int j = 0; j < 4; ++j) {
    int s = j * 256 + tid;
    int row = s >> 3, blk = (s & 7) ^ (row & 7);
    sA[j] = (m0 + row) * K + blk * 8;
    sB[j] = (n0 + row) * K + blk * 8;
    ldso[j] = (unsigned)(j * 256 + w * 64) * 8;
  }

  if (which == 2) {
    for (int k0 = 0; k0 < K; k0 += 64) {
      __syncthreads();
#pragma unroll
      for (int j = 0; j < 4; ++j) {
        GLD16(A + sA[j] + k0, As + ldso[j]);
        GLD16(Bt + sB[j] + k0, Bs + ldso[j]);
      }
      __syncthreads();
#pragma unroll
      for (int kk = 0; kk < 2; ++kk) {
        bf16x8 af[4], bf[4];
#pragma unroll
        for (int mi = 0; mi < 4; ++mi) {
          int row = wm * 64 + mi * 16 + l16;
          int blk = (kk * 4 + lq) ^ (l16 & 7);
          af[mi] = *(const bf16x8*)(As + row * 64 + blk * 8);
        }
#pragma unroll
        for (int ni = 0; ni < 4; ++ni) {
          int row = wn * 64 + ni * 16 + l16;
          int blk = (kk * 4 + lq) ^ (l16 & 7);
          bf[ni] = *(const bf16x8*)(Bs + row * 64 + blk * 8);
        }
#pragma unroll
        for (int ni = 0; ni < 4; ++ni)
#pragma unroll
          for (int mi = 0; mi < 4; ++mi)
            acc[mi][ni] = MFMA16(af[mi], bf[ni], acc[mi][ni], 0, 0, 0);
      }
    }
    // V: D[t(packed)][col]; bounce to [d][t] LDS, coalesced 128B-segment store
    float bv[4];
#pragma unroll
    for (int ni = 0; ni < 4; ++ni) bv[ni] = bias[n0 + wn * 64 + ni * 16 + l16];
    __syncthreads();
    unsigned short* E = SH + w * 2304;  // 32 rows x stride 72 (144B, 16B-mult)
    const int bh = (m0 >> 11) * 16 + ((n0 & 1023) >> 6) + wn;
    const int tt0 = (m0 & 2047) + wm * 64;
#pragma unroll
    for (int p = 0; p < 2; ++p) {
#pragma unroll
      for (int n2 = 0; n2 < 2; ++n2) {
        int ni = p * 2 + n2;
#pragma unroll
        for (int mi = 0; mi < 4; ++mi) {
          floatx4 vv = acc[mi][ni] + bv[ni];
          *(bf16x4*)(E + (n2 * 16 + l16) * 72 + mi * 16 + lq * 4) =
              __builtin_convertvector(vv, bf16x4);
        }
      }
#pragma unroll
      for (int s = 0; s < 4; ++s) {
        int dl = s * 8 + (l >> 3);
        bf16x8 vv = *(const bf16x8*)(E + dl * 72 + (l & 7) * 8);
        *(bf16x8*)(Vt + ((size_t)bh * 64 + p * 32 + dl) * 2048 + tt0 +
                   (l & 7) * 8) = vv;
      }
    }
  } else {
    for (int k0 = 0; k0 < K; k0 += 64) {
      __syncthreads();
#pragma unroll
      for (int j = 0; j < 4; ++j) {
        GLD16(A + sA[j] + k0, As + ldso[j]);
        GLD16(Bt + sB[j] + k0, Bs + ldso[j]);
      }
      __syncthreads();
#pragma unroll
      for (int kk = 0; kk < 2; ++kk) {
        bf16x8 af[4], bf[4];
#pragma unroll
        for (int mi = 0; mi < 4; ++mi) {
          int row = wm * 64 + mi * 16 + l16;
          int blk = (kk * 4 + lq) ^ (l16 & 7);
          af[mi] = *(const bf16x8*)(As + row * 64 + blk * 8);
        }
#pragma unroll
        for (int ni = 0; ni < 4; ++ni) {
          int row = wn * 64 + ni * 16 + l16;
          int blk = (kk * 4 + lq) ^ (l16 & 7);
          bf[ni] = *(const bf16x8*)(Bs + row * 64 + blk * 8);
        }
#pragma unroll
        for (int ni = 0; ni < 4; ++ni)
#pragma unroll
          for (int mi = 0; mi < 4; ++mi)
            acc[mi][ni] = MFMA16(bf[ni], af[mi], acc[mi][ni], 0, 0, 0);
      }
    }
    // Q/K: D[col(packed d)][t]; bounce to [t][d] LDS, coalesced 1KB stores
    const float sc = (which == 0) ? 0.7213475204444817f : 1.0f;
    unsigned short* dst = (which == 0) ? Q : Kc;
    __syncthreads();
    unsigned short* E = SH + w * 2304;
    const int bh = (m0 >> 11) * 16 + ((n0 & 1023) >> 6) + wn;
    const size_t gbase = ((size_t)bh * 2048 + (m0 & 2047) + wm * 64) * 64;
#pragma unroll
    for (int p = 0; p < 2; ++p) {
#pragma unroll
      for (int m2 = 0; m2 < 2; ++m2) {
        int mi = p * 2 + m2;
#pragma unroll
        for (int ni = 0; ni < 4; ++ni) {
          int col0 = n0 + wn * 64 + ni * 16 + lq * 4;
          floatx4 bv = *(const floatx4*)(bias + col0);
          floatx4 vv = (acc[mi][ni] + bv) * sc;
          *(bf16x4*)(E + (m2 * 16 + l16) * 72 + ni * 16 + lq * 4) =
              __builtin_convertvector(vv, bf16x4);
        }
      }
#pragma unroll
      for (int s = 0; s < 4; ++s) {
        int rl = s * 8 + (l >> 3);
        bf16x8 vv = *(const bf16x8*)(E + rl * 72 + (l & 7) * 8);
        *(bf16x8*)(dst + gbase + (size_t)(p * 32 + rl) * 64 + (l & 7) * 8) =
            vv;
      }
    }
  }
}

// ---------------- attention: 128 q/block, 2 q-waves x 2 k-halves, 2 blk/CU --
// P stays in registers: S^T C-frag (k = ct*16 + lq*4 + j per lane) IS the
// B-frag layout of v_mfma_f32_16x16x16_bf16 for k-tile ct, so PV runs as
// 4 K=16 MFMAs per (dt,qs) with no P LDS round-trip.
__global__ __launch_bounds__(256, 2) void attn_kernel(
    const unsigned short* __restrict__ Q,
    const unsigned short* __restrict__ Kc,
    const unsigned short* __restrict__ Vt,
    unsigned short* __restrict__ AO) {
  const int T = 2048;
  const int bh = blockIdx.y, q0 = blockIdx.x * 128;
  const int tid = threadIdx.x, w = tid >> 6, l = tid & 63;
  const int l16 = l & 15, lq = l >> 4;
  const int kh = w >> 1, wq = w & 1;  // k-half, q-wave
  const int h128 = tid & 127;

  __shared__ __align__(16) unsigned short KVs[2][2][2][4096];  // 64 KB
  __shared__ __align__(16) float Lred[512];                    // 2 KB

  // Q fragments (row-major, scale+log2e pre-folded)
  bf16x8 qf[4][2];
  {
    const unsigned short* qb = Q + ((size_t)bh * T + q0 + wq * 64) * 64;
#pragma unroll
    for (int qs = 0; qs < 4; ++qs) {
      const unsigned short* qr = qb + (qs * 16 + l16) * 64;
      qf[qs][0] = *(const bf16x8*)(qr + lq * 8);
      qf[qs][1] = *(const bf16x8*)(qr + 32 + lq * 8);
    }
  }

  float l_lane[4] = {0.f, 0.f, 0.f, 0.f};
  floatx4 o_acc[4][4] = {};

  const unsigned short* kbase = Kc + (size_t)bh * T * 64;
  const unsigned short* vbase = Vt + (size_t)bh * 64 * T;
  int kro[4], vro[4];
  unsigned ldso[4];
#pragma unroll
  for (int j = 0; j < 4; ++j) {
    int s = j * 128 + h128;
    int row = s >> 3, blk = (s & 7) ^ (row & 7);
    kro[j] = row * 64 + blk * 8;   // + chunk*4096
    vro[j] = row * T + blk * 8;    // + chunk*64
    ldso[j] = (unsigned)(j * 128 + wq * 64) * 8;
  }

  const int swz0 = (0 + lq) ^ (l16 & 7);
  const int swz1 = (4 + lq) ^ (l16 & 7);

  {
    int c0 = kh * 16;
#pragma unroll
    for (int j = 0; j < 4; ++j) {
      GLD16(kbase + c0 * 4096 + kro[j], &KVs[0][kh][0][ldso[j]]);
      GLD16(vbase + c0 * 64 + vro[j], &KVs[1][kh][0][ldso[j]]);
    }
  }

  for (int it = 0; it < 16; ++it) {
    __syncthreads();
    if (it + 1 < 16) {
      int cn = kh * 16 + it + 1, nb = (it + 1) & 1;
#pragma unroll
      for (int j = 0; j < 4; ++j) {
        GLD16(kbase + cn * 4096 + kro[j], &KVs[0][kh][nb][ldso[j]]);
        GLD16(vbase + cn * 64 + vro[j], &KVs[1][kh][nb][ldso[j]]);
      }
    }
    const unsigned short* kb = KVs[0][kh][it & 1];
    const unsigned short* vb = KVs[1][kh][it & 1];

    bf16x8 kf[4][2];
#pragma unroll
    for (int ct = 0; ct < 4; ++ct) {
      const unsigned short* kr = kb + (ct * 16 + l16) * 64;
      kf[ct][0] = *(const bf16x8*)(kr + swz0 * 8);
      kf[ct][1] = *(const bf16x8*)(kr + swz1 * 8);
    }

    // per-qs: S^T -> exp2 -> bf16 P fragments, all in registers
    bf16x4 pf[4][4];
#pragma unroll
    for (int qs = 0; qs < 4; ++qs) {
      floatx4 st[4];
#pragma unroll
      for (int ct = 0; ct < 4; ++ct) {
        floatx4 z = {};
        z = MFMA16(kf[ct][0], qf[qs][0], z, 0, 0, 0);
        z = MFMA16(kf[ct][1], qf[qs][1], z, 0, 0, 0);
        st[ct] = z;
      }
#pragma unroll
      for (int ct = 0; ct < 4; ++ct) {
        floatx4 pv;
        pv[0] = __builtin_amdgcn_exp2f(st[ct][0]);
        pv[1] = __builtin_amdgcn_exp2f(st[ct][1]);
        pv[2] = __builtin_amdgcn_exp2f(st[ct][2]);
        pv[3] = __builtin_amdgcn_exp2f(st[ct][3]);
        l_lane[qs] += (pv[0] + pv[1]) + (pv[2] + pv[3]);
        pf[qs][ct] = __builtin_convertvector(pv, bf16x4);
      }
    }

    // O^T += V^T * P^T via K=16 MFMAs (A = V^T b64 frags, B = pf in regs)
    const int vs = l16 & 7;
#pragma unroll
    for (int dt = 0; dt < 4; ++dt) {
      const unsigned short* vr = vb + (dt * 16 + l16) * 64 + (lq & 1) * 4;
      bf16x4 vf[4];
#pragma unroll
      for (int ct = 0; ct < 4; ++ct)
        vf[ct] = *(const bf16x4*)(vr + (((2 * ct + (lq >> 1)) ^ vs) << 3));
#pragma unroll
      for (int qs = 0; qs < 4; ++qs)
#pragma unroll
        for (int ct = 0; ct < 4; ++ct)
          o_acc[dt][qs] = MFMAPV(vf[ct], pf[qs][ct], o_acc[dt][qs]);
    }
  }

  // ---- combine the two k-halves (no-max softmax partials are additive) ----
  __syncthreads();
  float* ex = (float*)&KVs[0][0][0][0];  // 2 x 16 KB regions (K buffers dead)
  if (kh == 1) {
    float* r = ex + wq * 4096;
#pragma unroll
    for (int dt = 0; dt < 4; ++dt)
#pragma unroll
      for (int qs = 0; qs < 4; ++qs)
        *(floatx4*)(r + ((dt * 4 + qs) * 64 + l) * 4) = o_acc[dt][qs];
#pragma unroll
    for (int qs = 0; qs < 4; ++qs) Lred[(wq * 4 + qs) * 64 + l] = l_lane[qs];
  }
  __syncthreads();
  if (kh == 0) {
    const float* r = ex + wq * 4096;
    const int b = bh >> 4, h = bh & 15;
#pragma unroll
    for (int qs = 0; qs < 4; ++qs) {
      float ls = l_lane[qs] + Lred[(wq * 4 + qs) * 64 + l];
      ls += __shfl_xor(ls, 16, 64);
      ls += __shfl_xor(ls, 32, 64);
      float inv = 1.0f / ls;
      int t = q0 + wq * 64 + qs * 16 + l16;
#pragma unroll
      for (int dt = 0; dt < 4; ++dt) {
        floatx4 ov = o_acc[dt][qs] +
                     *(const floatx4*)(r + ((dt * 4 + qs) * 64 + l) * 4);
        ov *= inv;
        bf16x4 ob = __builtin_convertvector(ov, bf16x4);
        *(bf16x4*)(AO + ((size_t)b * 2048 + t) * 1024 + h * 64 + dt * 16 +
                   lq * 4) = ob;
      }
    }
  }
}

// ---------------- GEMM2: out = AO @ WprojT^T + bproj, swapped -> float4 -----
__global__ __launch_bounds__(256) void gemm_proj(
    const unsigned short* __restrict__ A,
    const unsigned short* __restrict__ Bt,
    const float* __restrict__ bias,
    float* __restrict__ out) {
  const int K = 1024, N = 1024;
  const int m0 = blockIdx.y * 128, n0 = blockIdx.x * 64;
  const int tid = threadIdx.x, w = tid >> 6, l = tid & 63;
  const int l16 = l & 15, lq = l >> 4;

  __shared__ __align__(16) unsigned short As[128 * 64];
  __shared__ __align__(16) unsigned short Bs[64 * 64];

  floatx4 acc[2][4] = {};

  int sA[4], sB[2];
  unsigned ldsoA[4], ldsoB[2];
#pragma unroll
  for (int j = 0; j < 4; ++j) {
    int s = j * 256 + tid;
    int row = s >> 3, blk = (s & 7) ^ (row & 7);
    sA[j] = (m0 + row) * K + blk * 8;
    ldsoA[j] = (unsigned)(j * 256 + w * 64) * 8;
  }
#pragma unroll
  for (int j = 0; j < 2; ++j) {
    int s = j * 256 + tid;
    int row = s >> 3, blk = (s & 7) ^ (row & 7);
    sB[j] = (n0 + row) * K + blk * 8;
    ldsoB[j] = (unsigned)(j * 256 + w * 64) * 8;
  }

  for (int k0 = 0; k0 < K; k0 += 64) {
    __syncthreads();
#pragma unroll
    for (int j = 0; j < 4; ++j) GLD16(A + sA[j] + k0, As + ldsoA[j]);
#pragma unroll
    for (int j = 0; j < 2; ++j) GLD16(Bt + sB[j] + k0, Bs + ldsoB[j]);
    __syncthreads();
#pragma unroll
    for (int kk = 0; kk < 2; ++kk) {
      bf16x8 af[2], bf[4];
#pragma unroll
      for (int mi = 0; mi < 2; ++mi) {
        int row = w * 32 + mi * 16 + l16;
        int blk = (kk * 4 + lq) ^ (l16 & 7);
        af[mi] = *(const bf16x8*)(As + row * 64 + blk * 8);
      }
#pragma unroll
      for (int ni = 0; ni < 4; ++ni) {
        int row = ni * 16 + l16;
        int blk = (kk * 4 + lq) ^ (l16 & 7);
        bf[ni] = *(const bf16x8*)(Bs + row * 64 + blk * 8);
      }
#pragma unroll
      for (int ni = 0; ni < 4; ++ni)
#pragma unroll
        for (int mi = 0; mi < 2; ++mi)
          acc[mi][ni] = MFMA16(bf[ni], af[mi], acc[mi][ni], 0, 0, 0);
    }
  }

#pragma unroll
  for (int mi = 0; mi < 2; ++mi) {
    int t = m0 + w * 32 + mi * 16 + l16;
#pragma unroll
    for (int ni = 0; ni < 4; ++ni) {
      int col0 = n0 + ni * 16 + lq * 4;
      floatx4 bv = *(const floatx4*)(bias + col0);
      *(floatx4*)(out + (size_t)t * N + col0) = acc[mi][ni] + bv;
    }
  }
}

extern "C" void kernel_launch(void* const* d_in, const int* in_sizes, int n_in,
                              void* d_out, int out_size, void* d_ws,
                              size_t ws_size, hipStream_t stream) {
  const float* x     = (const float*)d_in[0];
  const float* Wqkv  = (const float*)d_in[1];
  const float* bqkv  = (const float*)d_in[2];
  const float* Wproj = (const float*)d_in[3];
  const float* bproj = (const float*)d_in[4];
  float* out = (float*)d_out;

  unsigned short* Xb     = (unsigned short*)d_ws;  // 4096x1024
  unsigned short* Wqkvt  = Xb + 4194304;           // 3072x1024 (transposed)
  unsigned short* Wprojt = Wqkvt + 3145728;        // 1024x1024 (transposed)
  unsigned short* Qb     = Wprojt + 1048576;       // 32x2048x64 (pre-scaled)
  unsigned short* Kb     = Qb + 4194304;           // 32x2048x64
  unsigned short* Vtb    = Kb + 4194304;           // 32x64x2048
  unsigned short* AOb    = Vtb + 4194304;          // 4096x1024

  prologue_kernel<<<5120, 256, 0, stream>>>(x, Xb, Wqkv, Wqkvt, Wproj, Wprojt);
  gemm_qkv<<<dim3(24, 32), 256, 0, stream>>>(Xb, Wqkvt, bqkv, Qb, Kb, Vtb);
  attn_kernel<<<dim3(16, 32), 256, 0, stream>>>(Qb, Kb, Vtb, AOb);
  gemm_proj<<<dim3(16, 32), 256, 0, stream>>>(AOb, Wprojt, bproj, out);
}